// Round 1
// baseline (5998.549 us; speedup 1.0000x reference)
//
#include <hip/hip_runtime.h>
#include <hip/hip_bf16.h>
#include <math.h>

#define B_  4
#define S_  2048
#define D_  2048
#define H_  16
#define G_  4
#define HD_ 128
#define HALF_ 64

// ---------------------------------------------------------------------------
// GEMM: C[M,N] = A[M,K] @ W[K,N] + bias[N]   (fp32, 128x128 tile, BK=16,
// 256 threads, 8x8 micro-tile, LDS padded to 132 floats/row)
// ---------------------------------------------------------------------------
__global__ __launch_bounds__(256) void gemm_bias_kernel(
    const float* __restrict__ A, const float* __restrict__ W,
    const float* __restrict__ bias, float* __restrict__ C,
    int M, int N, int K)
{
    __shared__ float As[16][132];   // [k][m], transposed on load
    __shared__ float Bs[16][132];   // [k][n]
    const int tid = threadIdx.x;
    const int tx = tid & 15, ty = tid >> 4;
    const int m0 = blockIdx.y * 128, n0 = blockIdx.x * 128;

    float acc[8][8];
#pragma unroll
    for (int i = 0; i < 8; ++i)
#pragma unroll
        for (int j = 0; j < 8; ++j) acc[i][j] = 0.f;

    for (int k0 = 0; k0 < K; k0 += 16) {
        // A tile: 128 rows x 16 k  (512 float4, 2/thread), scatter-transpose
#pragma unroll
        for (int i = 0; i < 2; ++i) {
            int idx4 = tid + 256 * i;
            int r = idx4 >> 2, c4 = (idx4 & 3) * 4;
            float4 av = *(const float4*)&A[(m0 + r) * K + k0 + c4];
            As[c4 + 0][r] = av.x; As[c4 + 1][r] = av.y;
            As[c4 + 2][r] = av.z; As[c4 + 3][r] = av.w;
        }
        // B tile: 16 rows x 128 n  (512 float4, 2/thread)
#pragma unroll
        for (int i = 0; i < 2; ++i) {
            int idx4 = tid + 256 * i;
            int r = idx4 >> 5, c4 = (idx4 & 31) * 4;
            *(float4*)&Bs[r][c4] = *(const float4*)&W[(k0 + r) * N + n0 + c4];
        }
        __syncthreads();
#pragma unroll
        for (int kk = 0; kk < 16; ++kk) {
            float4 a0 = *(const float4*)&As[kk][ty * 8];
            float4 a1 = *(const float4*)&As[kk][ty * 8 + 4];
            float4 b0 = *(const float4*)&Bs[kk][tx * 8];
            float4 b1 = *(const float4*)&Bs[kk][tx * 8 + 4];
            float a[8] = {a0.x, a0.y, a0.z, a0.w, a1.x, a1.y, a1.z, a1.w};
            float b[8] = {b0.x, b0.y, b0.z, b0.w, b1.x, b1.y, b1.z, b1.w};
#pragma unroll
            for (int i = 0; i < 8; ++i)
#pragma unroll
                for (int j = 0; j < 8; ++j)
                    acc[i][j] = fmaf(a[i], b[j], acc[i][j]);
        }
        __syncthreads();
    }
    // epilogue: bias add, float4 stores
#pragma unroll
    for (int i = 0; i < 8; ++i) {
        int row = m0 + ty * 8 + i;
        int col = n0 + tx * 8;
        float4 o0, o1;
        o0.x = acc[i][0] + bias[col + 0]; o0.y = acc[i][1] + bias[col + 1];
        o0.z = acc[i][2] + bias[col + 2]; o0.w = acc[i][3] + bias[col + 3];
        o1.x = acc[i][4] + bias[col + 4]; o1.y = acc[i][5] + bias[col + 5];
        o1.z = acc[i][6] + bias[col + 6]; o1.w = acc[i][7] + bias[col + 7];
        *(float4*)&C[(size_t)row * N + col]     = o0;
        *(float4*)&C[(size_t)row * N + col + 4] = o1;
    }
}

// ---------------------------------------------------------------------------
// RoPE (in-place) on a (B, S, nh, HD) buffer; half-split convention.
// Angle in fp64 for accuracy. `scale` additionally folds 1/sqrt(HD) into Q.
// ---------------------------------------------------------------------------
__global__ void rope_kernel(float* __restrict__ p, int nh, float scale, int total)
{
    int gid = blockIdx.x * 256 + threadIdx.x;
    if (gid >= total) return;
    int i = gid & 63;              // rotary pair index 0..63
    int rest = gid >> 6;
    int head = rest % nh;
    int rest2 = rest / nh;
    int s = rest2 & (S_ - 1);
    int b = rest2 >> 11;           // S_=2048
    int base = ((b * S_ + s) * nh + head) * HD_;

    double inv = pow(10000.0, -(double)i / 64.0);  // THETA^(-2i/HD)
    double ang = (double)s * inv;
    double sn, cs;
    sincos(ang, &sn, &cs);
    float t1 = p[base + i];
    float t2 = p[base + HALF_ + i];
    p[base + i]         = (float)((double)t1 * cs - (double)t2 * sn) * scale;
    p[base + HALF_ + i] = (float)((double)t2 * cs + (double)t1 * sn) * scale;
}

// ---------------------------------------------------------------------------
// Flash attention (causal, GQA). One block = 32 queries of one (b,h).
// Writes output IN-PLACE into the q buffer (each block only reads its own
// q tile, loaded to LDS first — safe).
// q: (B,S,H,HD) scaled+roped; k,v: (B,S,G,HD).
// ---------------------------------------------------------------------------
__global__ __launch_bounds__(256) void attn_kernel(
    float* q, const float* __restrict__ k, const float* __restrict__ v)
{
    __shared__ float Qs[32][132], Ks[32][132], Vs[32][132];
    __shared__ float Ss[32][36];
    __shared__ float ms[32], ls[32], alph[32];

    const int tid = threadIdx.x;
    const int qt  = (S_ / 32 - 1) - blockIdx.x;  // heavy blocks first
    const int bh  = blockIdx.y;
    const int b   = bh >> 4, h = bh & 15;
    const int g   = h >> 2;                      // H/G = 4

    // load Q tile (32 x 128): 1024 float4, 4 per thread
#pragma unroll
    for (int i = 0; i < 4; ++i) {
        int idx4 = tid + 256 * i;
        int r = idx4 >> 5, c4 = (idx4 & 31) * 4;
        *(float4*)&Qs[r][c4] =
            *(const float4*)&q[((b * S_ + qt * 32 + r) * H_ + h) * HD_ + c4];
    }
    if (tid < 32) { ms[tid] = -INFINITY; ls[tid] = 0.f; }

    float oacc[16];
#pragma unroll
    for (int t = 0; t < 16; ++t) oacc[t] = 0.f;

    const int qrow = tid >> 3, d0 = (tid & 7) * 16;   // PV mapping
    const int tq = (tid >> 4) * 2, tk2 = (tid & 15) * 2;  // score mapping

    for (int kt = 0; kt <= qt; ++kt) {
        __syncthreads();
        // load K/V tiles (each 32 x 128)
#pragma unroll
        for (int i = 0; i < 4; ++i) {
            int idx4 = tid + 256 * i;
            int r = idx4 >> 5, c4 = (idx4 & 31) * 4;
            int gaddr = ((b * S_ + kt * 32 + r) * G_ + g) * HD_ + c4;
            *(float4*)&Ks[r][c4] = *(const float4*)&k[gaddr];
            *(float4*)&Vs[r][c4] = *(const float4*)&v[gaddr];
        }
        __syncthreads();

        // scores: 2x2 micro-tile per thread over (32q x 32k)
        float s00 = 0, s01 = 0, s10 = 0, s11 = 0;
#pragma unroll
        for (int d4 = 0; d4 < 32; ++d4) {
            float4 qa = *(const float4*)&Qs[tq][d4 * 4];
            float4 qb = *(const float4*)&Qs[tq + 1][d4 * 4];
            float4 ka = *(const float4*)&Ks[tk2][d4 * 4];
            float4 kb = *(const float4*)&Ks[tk2 + 1][d4 * 4];
            s00 += qa.x * ka.x + qa.y * ka.y + qa.z * ka.z + qa.w * ka.w;
            s01 += qa.x * kb.x + qa.y * kb.y + qa.z * kb.z + qa.w * kb.w;
            s10 += qb.x * ka.x + qb.y * ka.y + qb.z * ka.z + qb.w * ka.w;
            s11 += qb.x * kb.x + qb.y * kb.y + qb.z * kb.z + qb.w * kb.w;
        }
        int qp0 = qt * 32 + tq, kp0 = kt * 32 + tk2;
        Ss[tq][tk2]         = (kp0     <= qp0)     ? s00 : -1e30f;
        Ss[tq][tk2 + 1]     = (kp0 + 1 <= qp0)     ? s01 : -1e30f;
        Ss[tq + 1][tk2]     = (kp0     <= qp0 + 1) ? s10 : -1e30f;
        Ss[tq + 1][tk2 + 1] = (kp0 + 1 <= qp0 + 1) ? s11 : -1e30f;
        __syncthreads();

        // online softmax row update (threads 0..31, one row each)
        if (tid < 32) {
            float mx = ms[tid];
#pragma unroll
            for (int j = 0; j < 32; ++j) mx = fmaxf(mx, Ss[tid][j]);
            float al = expf(ms[tid] - mx);
            float sum = 0.f;
#pragma unroll
            for (int j = 0; j < 32; ++j) {
                float pj = expf(Ss[tid][j] - mx);
                Ss[tid][j] = pj;
                sum += pj;
            }
            ls[tid] = ls[tid] * al + sum;
            ms[tid] = mx;
            alph[tid] = al;
        }
        __syncthreads();

        // O update: 8 threads per q-row, 16 d each
        float al = alph[qrow];
#pragma unroll
        for (int t = 0; t < 16; ++t) oacc[t] *= al;
        for (int kk = 0; kk < 32; ++kk) {
            float pkk = Ss[qrow][kk];
            float4 v0 = *(const float4*)&Vs[kk][d0];
            float4 v1 = *(const float4*)&Vs[kk][d0 + 4];
            float4 v2 = *(const float4*)&Vs[kk][d0 + 8];
            float4 v3 = *(const float4*)&Vs[kk][d0 + 12];
            oacc[0]  += pkk * v0.x; oacc[1]  += pkk * v0.y;
            oacc[2]  += pkk * v0.z; oacc[3]  += pkk * v0.w;
            oacc[4]  += pkk * v1.x; oacc[5]  += pkk * v1.y;
            oacc[6]  += pkk * v1.z; oacc[7]  += pkk * v1.w;
            oacc[8]  += pkk * v2.x; oacc[9]  += pkk * v2.y;
            oacc[10] += pkk * v2.z; oacc[11] += pkk * v2.w;
            oacc[12] += pkk * v3.x; oacc[13] += pkk * v3.y;
            oacc[14] += pkk * v3.z; oacc[15] += pkk * v3.w;
        }
    }

    float inv_l = 1.f / ls[qrow];
    int obase = ((b * S_ + qt * 32 + qrow) * H_ + h) * HD_ + d0;
#pragma unroll
    for (int j = 0; j < 4; ++j) {
        float4 ov;
        ov.x = oacc[4 * j + 0] * inv_l; ov.y = oacc[4 * j + 1] * inv_l;
        ov.z = oacc[4 * j + 2] * inv_l; ov.w = oacc[4 * j + 3] * inv_l;
        *(float4*)&q[obase + 4 * j] = ov;
    }
}

// ---------------------------------------------------------------------------
extern "C" void kernel_launch(void* const* d_in, const int* in_sizes, int n_in,
                              void* d_out, int out_size, void* d_ws, size_t ws_size,
                              hipStream_t stream)
{
    const float* x  = (const float*)d_in[0];
    const float* Wq = (const float*)d_in[1];
    const float* bq = (const float*)d_in[2];
    const float* Wk = (const float*)d_in[3];
    const float* bk = (const float*)d_in[4];
    const float* Wv = (const float*)d_in[5];
    const float* bv = (const float*)d_in[6];
    const float* Wo = (const float*)d_in[7];
    const float* bo = (const float*)d_in[8];
    float* out = (float*)d_out;

    float* ws = (float*)d_ws;
    float* qb = ws;                               // B*S*H*HD  = 16777216 f
    float* kb = ws + 16777216;                    // B*S*G*HD  =  4194304 f
    float* vb = ws + 16777216 + 4194304;          // B*S*G*HD  =  4194304 f
    // total ws use: 100.7 MB; attention output written in-place into qb

    const int M = B_ * S_;
    dim3 blk(256);

    // QKV projections (+ zero biases, but honored anyway)
    gemm_bias_kernel<<<dim3(D_ / 128, M / 128), blk, 0, stream>>>(
        x, Wq, bq, qb, M, H_ * HD_, D_);
    gemm_bias_kernel<<<dim3((G_ * HD_) / 128, M / 128), blk, 0, stream>>>(
        x, Wk, bk, kb, M, G_ * HD_, D_);
    gemm_bias_kernel<<<dim3((G_ * HD_) / 128, M / 128), blk, 0, stream>>>(
        x, Wv, bv, vb, M, G_ * HD_, D_);

    // RoPE: q also gets the 1/sqrt(HD) score scale folded in
    const float qscale = 0.08838834764831845f;    // 1/sqrt(128)
    int totq = M * H_ * HALF_;
    int totk = M * G_ * HALF_;
    rope_kernel<<<totq / 256, blk, 0, stream>>>(qb, H_, qscale, totq);
    rope_kernel<<<totk / 256, blk, 0, stream>>>(kb, G_, 1.0f, totk);

    // causal GQA flash attention; output overwrites qb
    attn_kernel<<<dim3(S_ / 32, B_ * H_), blk, 0, stream>>>(qb, kb, vb);

    // output projection
    gemm_bias_kernel<<<dim3(D_ / 128, M / 128), blk, 0, stream>>>(
        qb, Wo, bo, out, M, D_, H_ * HD_);
}

// Round 2
// 964.031 us; speedup vs baseline: 6.2224x; 6.2224x over previous
//
#include <hip/hip_runtime.h>
#include <hip/hip_bf16.h>
#include <math.h>

#define B_  4
#define S_  2048
#define D_  2048
#define H_  16
#define G_  4
#define HD_ 128

typedef __attribute__((ext_vector_type(8))) short short8;
typedef __attribute__((ext_vector_type(4))) float floatx4;

__device__ __forceinline__ short f2bf(float f) {
    unsigned u = __float_as_uint(f);
    unsigned r = (u + 0x7fff + ((u >> 16) & 1)) >> 16;
    return (short)r;
}
__device__ __forceinline__ float b2f(short s) {
    return __uint_as_float(((unsigned)(unsigned short)s) << 16);
}

#define GLL16(gp, lp) __builtin_amdgcn_global_load_lds( \
    (const __attribute__((address_space(1))) void*)(gp), \
    (__attribute__((address_space(3))) void*)(lp), 16, 0, 0)

// ---------------------------------------------------------------------------
// fp32 -> bf16 plain convert (8 elems/thread)
// ---------------------------------------------------------------------------
__global__ void cvt_bf16_kernel(const float* __restrict__ in,
                                short* __restrict__ out, int n8)
{
    int t = blockIdx.x * 256 + threadIdx.x;
    if (t >= n8) return;
    const float4* p = (const float4*)in + (size_t)t * 2;
    float4 a = p[0], b = p[1];
    short8 r;
    r[0] = f2bf(a.x); r[1] = f2bf(a.y); r[2] = f2bf(a.z); r[3] = f2bf(a.w);
    r[4] = f2bf(b.x); r[5] = f2bf(b.y); r[6] = f2bf(b.z); r[7] = f2bf(b.w);
    ((short8*)out)[t] = r;
}

// ---------------------------------------------------------------------------
// W[K][N] fp32 -> Wt[N][K] bf16, 32x32 LDS tiles
// ---------------------------------------------------------------------------
__global__ __launch_bounds__(256) void tr_bf16_kernel(
    const float* __restrict__ in, short* __restrict__ out, int K, int N)
{
    __shared__ float T[32][33];
    int n0 = blockIdx.x * 32, k0 = blockIdx.y * 32;
    int tx = threadIdx.x & 31, ty = threadIdx.x >> 5;   // ty 0..7
#pragma unroll
    for (int i = 0; i < 4; ++i)
        T[ty + i * 8][tx] = in[(size_t)(k0 + ty + i * 8) * N + n0 + tx];
    __syncthreads();
#pragma unroll
    for (int i = 0; i < 4; ++i)
        out[(size_t)(n0 + ty + i * 8) * K + k0 + tx] = f2bf(T[tx][ty + i * 8]);
}

// ---------------------------------------------------------------------------
// bf16 MFMA GEMM: C[M,N] = A[M,K] @ Bt[N,K]^T + bias.  m97 structure:
// 128x128 tile, BK=32, 4 waves (2x2), 4x4 16x16 frags/wave, global_load_lds.
// ---------------------------------------------------------------------------
template <bool OUT_BF16>
__global__ __launch_bounds__(256) void gemm_nt(
    const short* __restrict__ A, const short* __restrict__ Bt,
    const float* __restrict__ bias, void* __restrict__ Cv,
    int M, int N, int K)
{
    __shared__ short As[128 * 32];   // [m][k]  pitch 32 (global_load_lds: no pad)
    __shared__ short Bs[128 * 32];   // [n][k]
    const int tid = threadIdx.x;
    const int w = tid >> 6, l15 = tid & 15, quad = (tid & 63) >> 4;
    const int wm = w >> 1, wn = w & 1;
    const int m0 = blockIdx.y * 128, n0 = blockIdx.x * 128;

    floatx4 zero = {0.f, 0.f, 0.f, 0.f};
    floatx4 acc[4][4];
#pragma unroll
    for (int i = 0; i < 4; ++i)
#pragma unroll
        for (int j = 0; j < 4; ++j) acc[i][j] = zero;

    const int arow = tid >> 2, akc = tid & 3;   // chunk = tid (+256)
    const short* Ag0 = A + (size_t)(m0 + arow) * K + akc * 8;
    const short* Ag1 = A + (size_t)(m0 + 64 + arow) * K + akc * 8;
    const short* Bg0 = Bt + (size_t)(n0 + arow) * K + akc * 8;
    const short* Bg1 = Bt + (size_t)(n0 + 64 + arow) * K + akc * 8;
    short* AsW0 = As + (w * 64) * 8;          // wave-uniform LDS bases
    short* AsW1 = As + (256 + w * 64) * 8;
    short* BsW0 = Bs + (w * 64) * 8;
    short* BsW1 = Bs + (256 + w * 64) * 8;

    for (int k0 = 0; k0 < K; k0 += 32) {
        GLL16(Ag0 + k0, AsW0);
        GLL16(Ag1 + k0, AsW1);
        GLL16(Bg0 + k0, BsW0);
        GLL16(Bg1 + k0, BsW1);
        __syncthreads();
        short8 af[4], bfr[4];
#pragma unroll
        for (int mt = 0; mt < 4; ++mt)
            af[mt] = *(const short8*)(As + (wm * 64 + mt * 16 + l15) * 32 + quad * 8);
#pragma unroll
        for (int nt = 0; nt < 4; ++nt)
            bfr[nt] = *(const short8*)(Bs + (wn * 64 + nt * 16 + l15) * 32 + quad * 8);
#pragma unroll
        for (int mt = 0; mt < 4; ++mt)
#pragma unroll
            for (int nt = 0; nt < 4; ++nt)
                acc[mt][nt] = __builtin_amdgcn_mfma_f32_16x16x32_bf16(
                    af[mt], bfr[nt], acc[mt][nt], 0, 0, 0);
        __syncthreads();
    }

#pragma unroll
    for (int nt = 0; nt < 4; ++nt) {
        int gcol = n0 + wn * 64 + nt * 16 + l15;
        float bv = bias[gcol];
#pragma unroll
        for (int mt = 0; mt < 4; ++mt) {
            int grow = m0 + wm * 64 + mt * 16 + quad * 4;
            floatx4 v = acc[mt][nt];
            if (OUT_BF16) {
                short* C = (short*)Cv;
#pragma unroll
                for (int r = 0; r < 4; ++r)
                    C[(size_t)(grow + r) * N + gcol] = f2bf(v[r] + bv);
            } else {
                float* C = (float*)Cv;
#pragma unroll
                for (int r = 0; r < 4; ++r)
                    C[(size_t)(grow + r) * N + gcol] = v[r] + bv;
            }
        }
    }
}

// ---------------------------------------------------------------------------
// RoPE in-place on bf16 (B,S,nh,HD); fp64 trig; scale folds 1/sqrt(HD) into q
// ---------------------------------------------------------------------------
__global__ void rope_bf16_kernel(short* __restrict__ p, int nh, float scale,
                                 int total)
{
    int gid = blockIdx.x * 256 + threadIdx.x;
    if (gid >= total) return;
    int i = gid & 63;
    int rest = gid >> 6;
    int head = rest % nh;
    int rest2 = rest / nh;
    int s = rest2 & (S_ - 1);
    int b = rest2 >> 11;
    size_t base = (((size_t)b * S_ + s) * nh + head) * HD_;
    double inv = pow(10000.0, -(double)i / 64.0);
    double ang = (double)s * inv;
    double sn, cs;
    sincos(ang, &sn, &cs);
    float t1 = b2f(p[base + i]), t2 = b2f(p[base + 64 + i]);
    p[base + i]      = f2bf((float)((double)t1 * cs - (double)t2 * sn) * scale);
    p[base + 64 + i] = f2bf((float)((double)t2 * cs + (double)t1 * sn) * scale);
}

// ---------------------------------------------------------------------------
// MFMA flash attention, causal, GQA. Block = 4 waves = 64 q-rows of one (b,h).
// Wave w owns rows q0+16w..+15: Q frags in regs, K tile LDS (pitch 136),
// V transposed LDS [dv][key] (pitch 56), P via per-wave LDS round-trip
// (pitch 56). Output written in-place into qb (block-private rows).
// ---------------------------------------------------------------------------
#define KP_ 136
#define VP_ 56
#define PP_ 56

__global__ __launch_bounds__(256) void attn_mfma(
    short* __restrict__ qb, const short* __restrict__ kb,
    const short* __restrict__ vb)
{
    __shared__ short Ks[32 * KP_];
    __shared__ short Vt[128 * VP_];
    __shared__ short Pb[4][16 * PP_];

    const int tid = threadIdx.x;
    const int w = tid >> 6, lane = tid & 63, l15 = lane & 15, quad = lane >> 4;
    const int qi = 31 - (int)blockIdx.x;          // heavy blocks first
    const int q0 = qi * 64;
    const int bh = blockIdx.y, b = bh >> 4, h = bh & 15, g = h >> 2;

    // Q fragments (A-layout): row = l15 of wave tile, k = quad*8+j
    const short* qp = qb + ((((size_t)b * S_) + q0 + w * 16 + l15) * H_ + h) * HD_
                      + quad * 8;
    short8 qf[4];
#pragma unroll
    for (int c = 0; c < 4; ++c) qf[c] = *(const short8*)(qp + c * 32);

    floatx4 ob[8];
#pragma unroll
    for (int nt = 0; nt < 8; ++nt) ob[nt] = (floatx4){0.f, 0.f, 0.f, 0.f};
    float m_i[4], l_i[4];
#pragma unroll
    for (int r = 0; r < 4; ++r) { m_i[r] = -1e30f; l_i[r] = 0.f; }

    const int kkey = tid >> 4, kkc = tid & 15;    // K staging: 2 chunks/thread
    const int vp = tid & 15, vo = tid >> 4;       // V staging: key-pair, dv-octet
    const size_t kv0 = (size_t)b * S_ * (G_ * HD_) + g * HD_;

    const int nkt = 2 * qi + 2;
    for (int kt = 0; kt < nkt; ++kt) {
        __syncthreads();
        // ---- stage K tile (32 keys x 128 d), padded pitch
#pragma unroll
        for (int r = 0; r < 2; ++r) {
            int key = kkey + r * 16;
            short8 kv = *(const short8*)(kb + kv0 +
                (size_t)(kt * 32 + key) * (G_ * HD_) + kkc * 8);
            *(short8*)(Ks + key * KP_ + kkc * 8) = kv;
        }
        // ---- stage V transposed: [dv][key], key-pairs packed as u32
        {
            const short* vsrc = vb + kv0 +
                (size_t)(kt * 32 + 2 * vp) * (G_ * HD_) + vo * 8;
            short8 v0 = *(const short8*)(vsrc);
            short8 v1 = *(const short8*)(vsrc + G_ * HD_);
            unsigned* VtW = (unsigned*)Vt;
#pragma unroll
            for (int j = 0; j < 8; ++j) {
                unsigned pk = ((unsigned)(unsigned short)v0[j]) |
                              ((unsigned)(unsigned short)v1[j] << 16);
                VtW[((vo * 8 + j) * VP_ + 2 * vp) >> 1] = pk;
            }
        }
        __syncthreads();

        // ---- scores: two 16x16 tiles over 32 keys, K-dim = 128
        floatx4 s0 = (floatx4){0.f, 0.f, 0.f, 0.f};
        floatx4 s1 = (floatx4){0.f, 0.f, 0.f, 0.f};
#pragma unroll
        for (int c = 0; c < 4; ++c) {
            short8 b0 = *(const short8*)(Ks + l15 * KP_ + c * 32 + quad * 8);
            short8 b1 = *(const short8*)(Ks + (16 + l15) * KP_ + c * 32 + quad * 8);
            s0 = __builtin_amdgcn_mfma_f32_16x16x32_bf16(qf[c], b0, s0, 0, 0, 0);
            s1 = __builtin_amdgcn_mfma_f32_16x16x32_bf16(qf[c], b1, s1, 0, 0, 0);
        }

        // ---- causal mask (diagonal region only; wave-uniform guard)
        const int qabs0 = q0 + w * 16 + quad * 4;
        if (kt * 32 + 31 > q0 + w * 16) {
            int ka = kt * 32 + l15;
#pragma unroll
            for (int r = 0; r < 4; ++r) {
                if (ka > qabs0 + r)      s0[r] = -1e30f;
                if (ka + 16 > qabs0 + r) s1[r] = -1e30f;
            }
        }

        // ---- online softmax (rows = quad*4+r, cols across 16 lanes of quad)
        float al[4];
#pragma unroll
        for (int r = 0; r < 4; ++r) {
            float mx = fmaxf(s0[r], s1[r]);
#pragma unroll
            for (int off = 1; off < 16; off <<= 1)
                mx = fmaxf(mx, __shfl_xor(mx, off));
            float mn = fmaxf(m_i[r], mx);
            al[r] = __expf(m_i[r] - mn);
            m_i[r] = mn;
            float p0 = __expf(s0[r] - mn), p1 = __expf(s1[r] - mn);
            s0[r] = p0; s1[r] = p1;
            float rs = p0 + p1;
#pragma unroll
            for (int off = 1; off < 16; off <<= 1)
                rs += __shfl_xor(rs, off);
            l_i[r] = l_i[r] * al[r] + rs;
        }
#pragma unroll
        for (int nt = 0; nt < 8; ++nt) {
            floatx4 o = ob[nt];
            o[0] *= al[0]; o[1] *= al[1]; o[2] *= al[2]; o[3] *= al[3];
            ob[nt] = o;
        }

        // ---- P: C-layout -> bf16 -> per-wave LDS -> A-layout
        short* pw = Pb[w];
#pragma unroll
        for (int r = 0; r < 4; ++r) {
            pw[(quad * 4 + r) * PP_ + l15]      = f2bf(s0[r]);
            pw[(quad * 4 + r) * PP_ + 16 + l15] = f2bf(s1[r]);
        }
        short8 pf = *(const short8*)(pw + l15 * PP_ + quad * 8);

        // ---- PV: O[q][dv] += P @ V  (8 dv-tiles)
#pragma unroll
        for (int nt = 0; nt < 8; ++nt) {
            short8 vf = *(const short8*)(Vt + (nt * 16 + l15) * VP_ + quad * 8);
            ob[nt] = __builtin_amdgcn_mfma_f32_16x16x32_bf16(pf, vf, ob[nt], 0, 0, 0);
        }
    }

    // ---- epilogue: normalize, write bf16 in-place into qb
    float inv_l[4];
#pragma unroll
    for (int r = 0; r < 4; ++r) inv_l[r] = 1.f / l_i[r];
    size_t orow = (((size_t)b * S_) + q0 + w * 16 + quad * 4) * (H_ * HD_)
                  + h * HD_;
#pragma unroll
    for (int nt = 0; nt < 8; ++nt)
#pragma unroll
        for (int r = 0; r < 4; ++r)
            qb[orow + (size_t)r * (H_ * HD_) + nt * 16 + l15] =
                f2bf(ob[nt][r] * inv_l[r]);
}

// ---------------------------------------------------------------------------
extern "C" void kernel_launch(void* const* d_in, const int* in_sizes, int n_in,
                              void* d_out, int out_size, void* d_ws, size_t ws_size,
                              hipStream_t stream)
{
    const float* x  = (const float*)d_in[0];
    const float* Wq = (const float*)d_in[1];
    const float* bq = (const float*)d_in[2];
    const float* Wk = (const float*)d_in[3];
    const float* bk = (const float*)d_in[4];
    const float* Wv = (const float*)d_in[5];
    const float* bv = (const float*)d_in[6];
    const float* Wo = (const float*)d_in[7];
    const float* bo = (const float*)d_in[8];
    float* out = (float*)d_out;

    // ws layout (bf16 elements); total 96.5 MB
    short* xb  = (short*)d_ws;        // M*D        = 16,777,216
    short* sA  = xb  + 16777216;      // shared slot: Wqt then Wot (4,194,304)
    short* Wkt = sA  + 4194304;       // 1,048,576
    short* Wvt = Wkt + 1048576;       // 1,048,576
    short* qb8 = Wvt + 1048576;       // 16,777,216  (q -> attn out, in-place)
    short* kb8 = qb8 + 16777216;      // 4,194,304
    short* vb8 = kb8 + 4194304;       // 4,194,304

    const int M = B_ * S_;
    dim3 blk(256);

    cvt_bf16_kernel<<<8192, blk, 0, stream>>>(x, xb, 16777216 / 8);
    tr_bf16_kernel<<<dim3(64, 64), blk, 0, stream>>>(Wq, sA,  2048, 2048);
    tr_bf16_kernel<<<dim3(16, 64), blk, 0, stream>>>(Wk, Wkt, 2048, 512);
    tr_bf16_kernel<<<dim3(16, 64), blk, 0, stream>>>(Wv, Wvt, 2048, 512);

    gemm_nt<true><<<dim3(16, 64), blk, 0, stream>>>(xb, sA,  bq, qb8, M, 2048, 2048);
    gemm_nt<true><<<dim3(4, 64),  blk, 0, stream>>>(xb, Wkt, bk, kb8, M, 512, 2048);
    gemm_nt<true><<<dim3(4, 64),  blk, 0, stream>>>(xb, Wvt, bv, vb8, M, 512, 2048);

    // Wq no longer needed -> reuse slot for Wo^T (stream-ordered)
    tr_bf16_kernel<<<dim3(64, 64), blk, 0, stream>>>(Wo, sA, 2048, 2048);

    const float qscale = 0.08838834764831845f;   // 1/sqrt(128)
    rope_bf16_kernel<<<32768, blk, 0, stream>>>(qb8, H_, qscale, M * H_ * 64);
    rope_bf16_kernel<<<8192,  blk, 0, stream>>>(kb8, G_, 1.0f,   M * G_ * 64);

    attn_mfma<<<dim3(32, 64), blk, 0, stream>>>(qb8, kb8, vb8);

    gemm_nt<false><<<dim3(16, 64), blk, 0, stream>>>(qb8, sA, bo, out, M, 2048, 2048);
}

// Round 3
// 744.259 us; speedup vs baseline: 8.0598x; 1.2953x over previous
//
#include <hip/hip_runtime.h>
#include <hip/hip_bf16.h>
#include <math.h>

#define B_  4
#define S_  2048
#define D_  2048
#define H_  16
#define G_  4
#define HD_ 128

typedef __attribute__((ext_vector_type(8))) short short8;
typedef __attribute__((ext_vector_type(4))) float floatx4;

__device__ __forceinline__ short f2bf(float f) {
    unsigned u = __float_as_uint(f);
    unsigned r = (u + 0x7fff + ((u >> 16) & 1)) >> 16;
    return (short)r;
}
__device__ __forceinline__ float b2f(short s) {
    return __uint_as_float(((unsigned)(unsigned short)s) << 16);
}
// pack two floats to bf16x2, round-half-up (cheap; used for P)
__device__ __forceinline__ unsigned pk2(float a, float b) {
    unsigned ua = (__float_as_uint(a) + 0x8000u) >> 16;
    unsigned ub = (__float_as_uint(b) + 0x8000u) & 0xffff0000u;
    return ua | ub;
}
// pack two floats to bf16x2, RNE (outputs)
__device__ __forceinline__ unsigned pkr(float a, float b) {
    return (unsigned)(unsigned short)f2bf(a) |
           ((unsigned)(unsigned short)f2bf(b) << 16);
}

#define GLL16(gp, lp) __builtin_amdgcn_global_load_lds( \
    (const __attribute__((address_space(1))) void*)(gp), \
    (__attribute__((address_space(3))) void*)(lp), 16, 0, 0)

// ---------------------------------------------------------------------------
// fp32 -> bf16 convert (8 elems/thread)
// ---------------------------------------------------------------------------
__global__ void cvt_bf16_kernel(const float* __restrict__ in,
                                short* __restrict__ out, int n8)
{
    int t = blockIdx.x * 256 + threadIdx.x;
    if (t >= n8) return;
    const float4* p = (const float4*)in + (size_t)t * 2;
    float4 a = p[0], b = p[1];
    short8 r;
    r[0] = f2bf(a.x); r[1] = f2bf(a.y); r[2] = f2bf(a.z); r[3] = f2bf(a.w);
    r[4] = f2bf(b.x); r[5] = f2bf(b.y); r[6] = f2bf(b.z); r[7] = f2bf(b.w);
    ((short8*)out)[t] = r;
}

// ---------------------------------------------------------------------------
// W[K][N] fp32 -> Wt[N][K] bf16, 32x32 LDS tiles
// ---------------------------------------------------------------------------
__global__ __launch_bounds__(256) void tr_bf16_kernel(
    const float* __restrict__ in, short* __restrict__ out, int K, int N)
{
    __shared__ float T[32][33];
    int n0 = blockIdx.x * 32, k0 = blockIdx.y * 32;
    int tx = threadIdx.x & 31, ty = threadIdx.x >> 5;
#pragma unroll
    for (int i = 0; i < 4; ++i)
        T[ty + i * 8][tx] = in[(size_t)(k0 + ty + i * 8) * N + n0 + tx];
    __syncthreads();
#pragma unroll
    for (int i = 0; i < 4; ++i)
        out[(size_t)(n0 + ty + i * 8) * K + k0 + tx] = f2bf(T[tx][ty + i * 8]);
}

// ---------------------------------------------------------------------------
// Merged QKV GEMM: [M,3072] = xb[M,2048] @ Wt[3072,2048]^T (+bias).
// n<2048 -> qb8 (b,s,h,hd); n<2560 -> kb8 (b,s,g,hd); else vt8 TRANSPOSED
// (b,g,dv,s) so attention can stage V^T with plain vector loads.
// ---------------------------------------------------------------------------
__global__ __launch_bounds__(256) void gemm_qkv(
    const short* __restrict__ A, const short* __restrict__ Bt,
    const float* __restrict__ bq, const float* __restrict__ bk,
    const float* __restrict__ bv, short* __restrict__ qout,
    short* __restrict__ kout, short* __restrict__ vout, int M, int N, int K)
{
    __shared__ short As[128 * 32];
    __shared__ short Bs[128 * 32];
    const int tid = threadIdx.x;
    const int w = tid >> 6, l15 = tid & 15, quad = (tid & 63) >> 4;
    const int wm = w >> 1, wn = w & 1;
    const int m0 = blockIdx.y * 128, n0 = blockIdx.x * 128;

    floatx4 acc[4][4];
#pragma unroll
    for (int i = 0; i < 4; ++i)
#pragma unroll
        for (int j = 0; j < 4; ++j) acc[i][j] = (floatx4){0.f, 0.f, 0.f, 0.f};

    const int arow = tid >> 2, akc = tid & 3;
    const short* Ag0 = A + (size_t)(m0 + arow) * K + akc * 8;
    const short* Ag1 = A + (size_t)(m0 + 64 + arow) * K + akc * 8;
    const short* Bg0 = Bt + (size_t)(n0 + arow) * K + akc * 8;
    const short* Bg1 = Bt + (size_t)(n0 + 64 + arow) * K + akc * 8;
    short* AsW0 = As + (w * 64) * 8;
    short* AsW1 = As + (256 + w * 64) * 8;
    short* BsW0 = Bs + (w * 64) * 8;
    short* BsW1 = Bs + (256 + w * 64) * 8;

    for (int k0 = 0; k0 < K; k0 += 32) {
        GLL16(Ag0 + k0, AsW0);
        GLL16(Ag1 + k0, AsW1);
        GLL16(Bg0 + k0, BsW0);
        GLL16(Bg1 + k0, BsW1);
        __syncthreads();
        short8 af[4], bfr[4];
#pragma unroll
        for (int mt = 0; mt < 4; ++mt)
            af[mt] = *(const short8*)(As + (wm * 64 + mt * 16 + l15) * 32 + quad * 8);
#pragma unroll
        for (int nt = 0; nt < 4; ++nt)
            bfr[nt] = *(const short8*)(Bs + (wn * 64 + nt * 16 + l15) * 32 + quad * 8);
#pragma unroll
        for (int mt = 0; mt < 4; ++mt)
#pragma unroll
            for (int nt = 0; nt < 4; ++nt)
                acc[mt][nt] = __builtin_amdgcn_mfma_f32_16x16x32_bf16(
                    af[mt], bfr[nt], acc[mt][nt], 0, 0, 0);
        __syncthreads();
    }

#pragma unroll
    for (int nt = 0; nt < 4; ++nt) {
        int gcol = n0 + wn * 64 + nt * 16 + l15;
        float bvv = (gcol < 2048) ? bq[gcol]
                  : (gcol < 2560) ? bk[gcol - 2048] : bv[gcol - 2560];
#pragma unroll
        for (int mt = 0; mt < 4; ++mt) {
            int grow = m0 + wm * 64 + mt * 16 + quad * 4;
            floatx4 v = acc[mt][nt];
            if (n0 < 2048) {
#pragma unroll
                for (int r = 0; r < 4; ++r)
                    qout[(size_t)(grow + r) * 2048 + gcol] = f2bf(v[r] + bvv);
            } else if (n0 < 2560) {
                int c = gcol - 2048;
#pragma unroll
                for (int r = 0; r < 4; ++r)
                    kout[(size_t)(grow + r) * 512 + c] = f2bf(v[r] + bvv);
            } else {
                int c = gcol - 2560, gg = c >> 7, dv = c & 127;
                int bb = grow >> 11, s = grow & 2047;
                uint2 pk;
                pk.x = pkr(v[0] + bvv, v[1] + bvv);
                pk.y = pkr(v[2] + bvv, v[3] + bvv);
                *(uint2*)&vout[(((size_t)bb * G_ + gg) * HD_ + dv) * S_ + s] = pk;
            }
        }
    }
}

// ---------------------------------------------------------------------------
// bf16 MFMA GEMM (O-projection): C[M,N] fp32 = A[M,K] @ Bt[N,K]^T + bias
// ---------------------------------------------------------------------------
__global__ __launch_bounds__(256) void gemm_nt_f32(
    const short* __restrict__ A, const short* __restrict__ Bt,
    const float* __restrict__ bias, float* __restrict__ C,
    int M, int N, int K)
{
    __shared__ short As[128 * 32];
    __shared__ short Bs[128 * 32];
    const int tid = threadIdx.x;
    const int w = tid >> 6, l15 = tid & 15, quad = (tid & 63) >> 4;
    const int wm = w >> 1, wn = w & 1;
    const int m0 = blockIdx.y * 128, n0 = blockIdx.x * 128;

    floatx4 acc[4][4];
#pragma unroll
    for (int i = 0; i < 4; ++i)
#pragma unroll
        for (int j = 0; j < 4; ++j) acc[i][j] = (floatx4){0.f, 0.f, 0.f, 0.f};

    const int arow = tid >> 2, akc = tid & 3;
    const short* Ag0 = A + (size_t)(m0 + arow) * K + akc * 8;
    const short* Ag1 = A + (size_t)(m0 + 64 + arow) * K + akc * 8;
    const short* Bg0 = Bt + (size_t)(n0 + arow) * K + akc * 8;
    const short* Bg1 = Bt + (size_t)(n0 + 64 + arow) * K + akc * 8;
    short* AsW0 = As + (w * 64) * 8;
    short* AsW1 = As + (256 + w * 64) * 8;
    short* BsW0 = Bs + (w * 64) * 8;
    short* BsW1 = Bs + (256 + w * 64) * 8;

    for (int k0 = 0; k0 < K; k0 += 32) {
        GLL16(Ag0 + k0, AsW0);
        GLL16(Ag1 + k0, AsW1);
        GLL16(Bg0 + k0, BsW0);
        GLL16(Bg1 + k0, BsW1);
        __syncthreads();
        short8 af[4], bfr[4];
#pragma unroll
        for (int mt = 0; mt < 4; ++mt)
            af[mt] = *(const short8*)(As + (wm * 64 + mt * 16 + l15) * 32 + quad * 8);
#pragma unroll
        for (int nt = 0; nt < 4; ++nt)
            bfr[nt] = *(const short8*)(Bs + (wn * 64 + nt * 16 + l15) * 32 + quad * 8);
#pragma unroll
        for (int mt = 0; mt < 4; ++mt)
#pragma unroll
            for (int nt = 0; nt < 4; ++nt)
                acc[mt][nt] = __builtin_amdgcn_mfma_f32_16x16x32_bf16(
                    af[mt], bfr[nt], acc[mt][nt], 0, 0, 0);
        __syncthreads();
    }

#pragma unroll
    for (int nt = 0; nt < 4; ++nt) {
        int gcol = n0 + wn * 64 + nt * 16 + l15;
        float bvv = bias[gcol];
#pragma unroll
        for (int mt = 0; mt < 4; ++mt) {
            int grow = m0 + wm * 64 + mt * 16 + quad * 4;
            floatx4 v = acc[mt][nt];
#pragma unroll
            for (int r = 0; r < 4; ++r)
                C[(size_t)(grow + r) * N + gcol] = v[r] + bvv;
        }
    }
}

// ---------------------------------------------------------------------------
// RoPE in-place on bf16 (B,S,nh,HD); fp32 trig (err 1e-4 << bf16 ulp)
// ---------------------------------------------------------------------------
__global__ void rope_bf16_kernel(short* __restrict__ p, int nh, float scale,
                                 int total)
{
    int gid = blockIdx.x * 256 + threadIdx.x;
    if (gid >= total) return;
    int i = gid & 63;
    int rest = gid >> 6;
    int head = rest % nh;
    int rest2 = rest / nh;
    int s = rest2 & (S_ - 1);
    int b = rest2 >> 11;
    size_t base = (((size_t)b * S_ + s) * nh + head) * HD_;
    float inv = __expf((float)i * -0.14391156509f);   // ln(1e4)/64
    float ang = (float)s * inv;
    float sn, cs;
    sincosf(ang, &sn, &cs);
    float t1 = b2f(p[base + i]), t2 = b2f(p[base + 64 + i]);
    p[base + i]      = f2bf((t1 * cs - t2 * sn) * scale);
    p[base + 64 + i] = f2bf((t2 * cs + t1 * sn) * scale);
}

// ---------------------------------------------------------------------------
// MFMA flash attention v2: S^T design.
// Block = 128 q-rows of one (b,h); wave = 32 q-rows; K-tile = 64 keys.
// S^T = K·Q^T  (C-layout col = lane's own query -> lane-local softmax state).
// O^T = V^T·P^T with V^T staged natural from the transposed global V buffer.
// K/V^T staged via global_load_lds(16B) with xor chunk-swizzle (GLL16 can't
// pad; swizzle turns 16-way bank conflicts into free 2-way).
// Output written in-place into qb (block-private rows).
// ---------------------------------------------------------------------------
#define PPITCH 72   // shorts; 144B = 16B-aligned, 4-bank stride -> 2-way

__global__ __launch_bounds__(256) void attn_mfma2(
    short* __restrict__ qb, const short* __restrict__ kb,
    const short* __restrict__ vt)
{
    __shared__ short Ks[64 * 128];      // [key][16B-chunk], chunk ^= key&7
    __shared__ short Vs[128 * 64];      // [dv][16B-chunk],  chunk ^= dv&7
    __shared__ short Ps[4][32 * PPITCH];// per-wave P as [q][key]

    const int tid = threadIdx.x;
    const int w = tid >> 6, lane = tid & 63, l15 = lane & 15, quad = lane >> 4;
    const int qi = 15 - (int)blockIdx.x;          // heavy blocks first
    const int q0 = qi * 128;
    const int bh = blockIdx.y, b = bh >> 4, h = bh & 15, g = h >> 2;

    // Q fragments: rows q0 + w*32 + qs*16 + l15, d = quad*8 + 32c
    const short* qp = qb + ((((size_t)b * S_) + q0 + w * 32 + l15) * H_ + h) * HD_
                      + quad * 8;
    short8 qf[2][4];
#pragma unroll
    for (int qs = 0; qs < 2; ++qs)
#pragma unroll
        for (int c = 0; c < 4; ++c)
            qf[qs][c] = *(const short8*)(qp + qs * 16 * (H_ * HD_) + c * 32);

    floatx4 ot[2][8];
#pragma unroll
    for (int qs = 0; qs < 2; ++qs)
#pragma unroll
        for (int s = 0; s < 8; ++s) ot[qs][s] = (floatx4){0.f, 0.f, 0.f, 0.f};
    float m_i[2] = {-1e30f, -1e30f}, l_i[2] = {0.f, 0.f};

    // staging maps
    const int kkey = tid >> 4, kch = tid & 15;
    const int ksrc = kch ^ (kkey & 7);            // (key+16i)&7 == kkey&7
    const short* kgb = kb + (((size_t)b * S_) * G_ + g) * HD_ + ksrc * 8;
    const int vdv = tid >> 3, vch = tid & 7;
    const int vsrc = vch ^ (vdv & 7);             // (dv+32i)&7 == vdv&7
    const short* vgb = vt + (((size_t)(b * G_ + g)) * HD_ + vdv) * (size_t)S_
                       + vsrc * 8;
    const int sw = l15 & 7;
    short* pw = Ps[w];

    const int nkt = 2 * (qi + 1);
    for (int kt = 0; kt < nkt; ++kt) {
        __syncthreads();
        const short* kg = kgb + (size_t)(kt * 64) * (G_ * HD_);
        const short* vg = vgb + kt * 64;
#pragma unroll
        for (int i = 0; i < 4; ++i)
            GLL16(kg + (size_t)(kkey + 16 * i) * (G_ * HD_),
                  Ks + (w * 64 + 256 * i) * 8);
#pragma unroll
        for (int i = 0; i < 4; ++i)
            GLL16(vg + (size_t)(32 * i) * S_, Vs + (w * 64 + 256 * i) * 8);
        __syncthreads();

        // ---- S^T tiles: sa[qs][ksub], row = key = ksub*16+quad*4+r, col = q = l15
        floatx4 sa[2][4];
#pragma unroll
        for (int qs = 0; qs < 2; ++qs)
#pragma unroll
            for (int ks = 0; ks < 4; ++ks) sa[qs][ks] = (floatx4){0.f, 0.f, 0.f, 0.f};
#pragma unroll
        for (int c = 0; c < 4; ++c)
#pragma unroll
            for (int ks = 0; ks < 4; ++ks) {
                short8 kf = *(const short8*)(Ks +
                    ((l15 + 16 * ks) * 16 + ((c * 4 + quad) ^ sw)) * 8);
                sa[0][ks] = __builtin_amdgcn_mfma_f32_16x16x32_bf16(
                    kf, qf[0][c], sa[0][ks], 0, 0, 0);
                sa[1][ks] = __builtin_amdgcn_mfma_f32_16x16x32_bf16(
                    kf, qf[1][c], sa[1][ks], 0, 0, 0);
            }

        const int kbase = kt * 64;
#pragma unroll
        for (int qs = 0; qs < 2; ++qs) {
            const int qrow = q0 + w * 32 + qs * 16 + l15;
            // causal mask (only near diagonal; uniform per qs)
            if (kbase + 63 > q0 + w * 32 + qs * 16) {
#pragma unroll
                for (int ks = 0; ks < 4; ++ks)
#pragma unroll
                    for (int r = 0; r < 4; ++r)
                        if (kbase + ks * 16 + quad * 4 + r > qrow)
                            sa[qs][ks][r] = -1e30f;
            }
            // ---- lane-local online softmax over this lane's 16 keys + 2 shfl
            float mx = -1e30f;
#pragma unroll
            for (int ks = 0; ks < 4; ++ks)
#pragma unroll
                for (int r = 0; r < 4; ++r) mx = fmaxf(mx, sa[qs][ks][r]);
            mx = fmaxf(mx, __shfl_xor(mx, 16));
            mx = fmaxf(mx, __shfl_xor(mx, 32));
            float mn = fmaxf(m_i[qs], mx);
            float al = __expf(m_i[qs] - mn);
            m_i[qs] = mn;
            float sum = 0.f;
#pragma unroll
            for (int ks = 0; ks < 4; ++ks)
#pragma unroll
                for (int r = 0; r < 4; ++r) {
                    float p = __expf(sa[qs][ks][r] - mn);
                    sa[qs][ks][r] = p;
                    sum += p;
                }
            sum += __shfl_xor(sum, 16);
            sum += __shfl_xor(sum, 32);
            l_i[qs] = l_i[qs] * al + sum;
#pragma unroll
            for (int s = 0; s < 8; ++s) {
                floatx4 o = ot[qs][s];
                o[0] *= al; o[1] *= al; o[2] *= al; o[3] *= al;
                ot[qs][s] = o;
            }
            // ---- P -> per-wave LDS as [q][key] (b64 writes)
            short* pr = pw + (qs * 16 + l15) * PPITCH;
#pragma unroll
            for (int ks = 0; ks < 4; ++ks) {
                uint2 pkv;
                pkv.x = pk2(sa[qs][ks][0], sa[qs][ks][1]);
                pkv.y = pk2(sa[qs][ks][2], sa[qs][ks][3]);
                *(uint2*)(pr + ks * 16 + quad * 4) = pkv;
            }
        }

        // ---- O^T += V^T · P^T  (V-frags shared across both q-subtiles)
#pragma unroll
        for (int kc = 0; kc < 2; ++kc) {
            short8 pf0 = *(const short8*)(pw + l15 * PPITCH + kc * 32 + quad * 8);
            short8 pf1 = *(const short8*)(pw + (16 + l15) * PPITCH + kc * 32 + quad * 8);
#pragma unroll
            for (int s = 0; s < 8; ++s) {
                short8 vf = *(const short8*)(Vs +
                    ((l15 + 16 * s) * 8 + ((kc * 4 + quad) ^ sw)) * 8);
                ot[0][s] = __builtin_amdgcn_mfma_f32_16x16x32_bf16(
                    vf, pf0, ot[0][s], 0, 0, 0);
                ot[1][s] = __builtin_amdgcn_mfma_f32_16x16x32_bf16(
                    vf, pf1, ot[1][s], 0, 0, 0);
            }
        }
    }

    // ---- epilogue: normalize (lane-local l), write bf16 in-place
#pragma unroll
    for (int qs = 0; qs < 2; ++qs) {
        float inv = 1.f / l_i[qs];
        size_t base = ((((size_t)b * S_) + q0 + w * 32 + qs * 16 + l15) * H_ + h)
                      * HD_;
#pragma unroll
        for (int s = 0; s < 8; ++s) {
            uint2 pkv;
            pkv.x = pkr(ot[qs][s][0] * inv, ot[qs][s][1] * inv);
            pkv.y = pkr(ot[qs][s][2] * inv, ot[qs][s][3] * inv);
            *(uint2*)&qb[base + s * 16 + quad * 4] = pkv;
        }
    }
}

// ---------------------------------------------------------------------------
extern "C" void kernel_launch(void* const* d_in, const int* in_sizes, int n_in,
                              void* d_out, int out_size, void* d_ws, size_t ws_size,
                              hipStream_t stream)
{
    const float* x  = (const float*)d_in[0];
    const float* Wq = (const float*)d_in[1];
    const float* bq = (const float*)d_in[2];
    const float* Wk = (const float*)d_in[3];
    const float* bk = (const float*)d_in[4];
    const float* Wv = (const float*)d_in[5];
    const float* bv = (const float*)d_in[6];
    const float* Wo = (const float*)d_in[7];
    const float* bo = (const float*)d_in[8];
    float* out = (float*)d_out;

    // ws layout (bf16 elements); total 96.5 MB
    short* xb  = (short*)d_ws;        // 16,777,216
    short* Wt  = xb + 16777216;       // 3072*2048 = 6,291,456 (reused for Wo^T)
    short* qb8 = Wt + 6291456;        // 16,777,216 (q -> attn out, in-place)
    short* kb8 = qb8 + 16777216;      // 4,194,304
    short* vt8 = kb8 + 4194304;       // 4,194,304  V^T (b,g,dv,s)

    const int M = B_ * S_;
    dim3 blk(256);

    cvt_bf16_kernel<<<8192, blk, 0, stream>>>(x, xb, 16777216 / 8);
    tr_bf16_kernel<<<dim3(64, 64), blk, 0, stream>>>(Wq, Wt, 2048, 2048);
    tr_bf16_kernel<<<dim3(16, 64), blk, 0, stream>>>(Wk, Wt + (size_t)2048 * 2048, 2048, 512);
    tr_bf16_kernel<<<dim3(16, 64), blk, 0, stream>>>(Wv, Wt + (size_t)2560 * 2048, 2048, 512);

    gemm_qkv<<<dim3(24, 64), blk, 0, stream>>>(xb, Wt, bq, bk, bv,
                                               qb8, kb8, vt8, M, 3072, 2048);

    // Wt slot free now -> Wo^T (stream-ordered)
    tr_bf16_kernel<<<dim3(64, 64), blk, 0, stream>>>(Wo, Wt, 2048, 2048);

    const float qscale = 0.08838834764831845f;   // 1/sqrt(128)
    rope_bf16_kernel<<<32768, blk, 0, stream>>>(qb8, H_, qscale, M * H_ * 64);
    rope_bf16_kernel<<<8192,  blk, 0, stream>>>(kb8, G_, 1.0f,   M * G_ * 64);

    attn_mfma2<<<dim3(16, 64), blk, 0, stream>>>(qb8, kb8, vt8);

    gemm_nt_f32<<<dim3(16, 64), blk, 0, stream>>>(qb8, Wt, bo, out, M, 2048, 2048);
}